// Round 3
// baseline (217.785 us; speedup 1.0000x reference)
//
#include <hip/hip_runtime.h>
#include <hip/hip_cooperative_groups.h>

namespace cg = cooperative_groups;

// GridMatch: A=8, B=8, N=2048, grid 640x480 per (a,b) image.
#define AD 8
#define BD 8
#define NP 2048
#define MPTS (AD*BD*NP)            // 131072 points
#define GRID_CAP 19660800LL        // 8*8*640*480 cells

// Grids store (point_id + 1); 0 == empty. Zero-initialized at module load;
// the clear phase restores zeros at the end of every call (deterministic).
__device__ int g_grid0[19660800];
__device__ int g_grid1[19660800];
__device__ int g_nm;               // match count
__device__ int g_cell[MPTS];       // unordered match records
__device__ int g_src[MPTS];
__device__ int g_dst[MPTS];

__global__ void k_all(const float* __restrict__ ps, const float* __restrict__ pd,
                      float* __restrict__ out,
                      const int* __restrict__ ph, const int* __restrict__ pw,
                      const int* __restrict__ pg) {
  cg::grid_group grid = cg::this_grid();
  int id = blockIdx.x * blockDim.x + threadIdx.x;   // 0..MPTS-1

  int h = *ph, w = *pw, gs = *pg;
  int gh = h * gs, gw = w * gs;
  float sx = (float)((gw - 1) * 0.5);
  float sy = (float)((gh - 1) * 0.5);
  int ab = id / NP;  // a*B + b

  // ---- phase 1: output defaults + compute cells + scatter ----
  if (id == 0) g_nm = 0;
  {
    float2* o01 = (float2*)out;
    o01[id]          = make_float2(0.f, 0.f);    // src_coord_m
    o01[MPTS + id]   = make_float2(0.f, 0.f);    // dst_coord_m
    o01[2*MPTS + id] = make_float2(-1.f, -1.f);  // src_bn
    o01[3*MPTS + id] = make_float2(-1.f, -1.f);  // dst_an
    out[8*MPTS + id] = 0.f;                      // valid
  }

  float spx = ps[2*id], spy = ps[2*id+1];
  float dpx = pd[2*id], dpy = pd[2*id+1];

  long long c0 = -1, c1 = -1;
  if (spx >= -1.f && spx <= 1.f && spy >= -1.f && spy <= 1.f) {
    long long c = ((long long)(ab * gw + (int)((spx + 1.f) * sx))) * gh
                  + (int)((spy + 1.f) * sy);
    if (c >= 0 && c < GRID_CAP) c0 = c;
  }
  if (dpx >= -1.f && dpx <= 1.f && dpy >= -1.f && dpy <= 1.f) {
    long long c = ((long long)(ab * gw + (int)((dpx + 1.f) * sx))) * gh
                  + (int)((dpy + 1.f) * sy);
    if (c >= 0 && c < GRID_CAP) c1 = c;
  }
  if (c0 >= 0) atomicMax(&g_grid0[c0], id + 1);
  if (c1 >= 0) atomicMax(&g_grid1[c1], id + 1);

  __threadfence();
  grid.sync();

  // ---- phase 2: collect (cell winners whose cell also holds a dst) ----
  if (c0 >= 0 && g_grid0[c0] == id + 1) {
    int v1 = g_grid1[c0];
    if (v1 != 0) {
      int slot = atomicAdd(&g_nm, 1);
      g_cell[slot] = (int)c0;
      g_src[slot]  = id;
      g_dst[slot]  = v1 - 1;
    }
  }

  __threadfence();
  grid.sync();

  // ---- phase 3a: clear touched cells (registers, no reload) ----
  if (c0 >= 0) g_grid0[c0] = 0;
  if (c1 >= 0) g_grid1[c1] = 0;

  // ---- phase 3b: emit matched rows at stable row-major ranks ----
  int n = g_nm; if (n > MPTS) n = MPTS;
  float fx = (float)((double)(h - 1) / (double)(gh - 1));  // pairs with x (faithful)
  float fy = (float)((double)(w - 1) / (double)(gw - 1));

  float* out0 = out;               // src_coord_m [M,2]
  float* out1 = out + 2*MPTS;      // dst_coord_m [M,2]
  float* out2 = out + 4*MPTS;      // src_bn      [M,2]
  float* out3 = out + 6*MPTS;      // dst_an      [M,2]
  float* out4 = out + 8*MPTS;      // valid       [M]

  int gsize = (int)(gridDim.x * blockDim.x);
  for (int i = id; i < n; i += gsize) {
    int ci = g_cell[i];
    int rank = 0;
    for (int j = 0; j < n; ++j) rank += (int)(g_cell[j] < ci);  // cells unique
    int s = g_src[i], d = g_dst[i];
    float ax = ps[2*s], ay = ps[2*s+1];
    out0[2*rank]   = (ax + 1.f) * sx * fx;
    out0[2*rank+1] = (ay + 1.f) * sy * fy;
    float bx = pd[2*d], by = pd[2*d+1];
    out1[2*rank]   = (bx + 1.f) * sx * fx;
    out1[2*rank+1] = (by + 1.f) * sy * fy;
    out2[2*rank]   = (float)((s / NP) % BD);
    out2[2*rank+1] = (float)(s % NP);
    out3[2*rank]   = (float)(d / (BD * NP));
    out3[2*rank+1] = (float)(d % NP);
    out4[rank]     = 1.f;
  }
}

extern "C" void kernel_launch(void* const* d_in, const int* in_sizes, int n_in,
                              void* d_out, int out_size, void* d_ws, size_t ws_size,
                              hipStream_t stream) {
  const float* ps = (const float*)d_in[0];
  const float* pd = (const float*)d_in[1];
  const int* ph = (const int*)d_in[2];
  const int* pw = (const int*)d_in[3];
  const int* pg = (const int*)d_in[4];
  float* out = (float*)d_out;

  void* args[] = {(void*)&ps, (void*)&pd, (void*)&out,
                  (void*)&ph, (void*)&pw, (void*)&pg};
  hipLaunchCooperativeKernel((const void*)k_all, dim3(MPTS/256), dim3(256),
                             args, 0, stream);
}

// Round 4
// 25.448 us; speedup vs baseline: 8.5580x; 8.5580x over previous
//
#include <hip/hip_runtime.h>

// GridMatch: A=8, B=8, N=2048, grid 640x480 per (a,b) image.
#define AD 8
#define BD 8
#define NP 2048
#define MPTS (AD*BD*NP)            // 131072 points
#define GRID_CAP 19660800LL        // 8*8*640*480 cells

// Grids store (point_id + 1); 0 == empty. Zero-initialized at module load;
// winners clear grid0 in k_collect, k_emit clears grid1 (deterministic:
// every call leaves both grids all-zero again).
__device__ int g_grid0[19660800];
__device__ int g_grid1[19660800];
__device__ int g_nm;               // match count (zeroed in k_scatter)
__device__ int g_c0[MPTS];         // saved cell index per point (-1 = invisible)
__device__ int g_c1[MPTS];
__device__ int g_cell[MPTS];       // unordered match records
__device__ int g_src[MPTS];
__device__ int g_dst[MPTS];

// ---- k1: compute cells, save them, scatter atomicMax(id+1) into grids ----
__global__ void k_scatter(const float* __restrict__ ps, const float* __restrict__ pd,
                          const int* __restrict__ ph, const int* __restrict__ pw,
                          const int* __restrict__ pg) {
  int id = blockIdx.x * blockDim.x + threadIdx.x;   // 0..MPTS-1
  if (id == 0) g_nm = 0;
  int h = *ph, w = *pw, gs = *pg;
  int gh = h * gs, gw = w * gs;
  float sx = (float)((gw - 1) * 0.5);
  float sy = (float)((gh - 1) * 0.5);
  int ab = id / NP;  // a*B + b

  float2 s = ((const float2*)ps)[id];
  float2 d = ((const float2*)pd)[id];

  int c0 = -1, c1 = -1;
  if (s.x >= -1.f && s.x <= 1.f && s.y >= -1.f && s.y <= 1.f) {
    long long c = ((long long)(ab * gw + (int)((s.x + 1.f) * sx))) * gh
                  + (int)((s.y + 1.f) * sy);
    if (c >= 0 && c < GRID_CAP) c0 = (int)c;
  }
  if (d.x >= -1.f && d.x <= 1.f && d.y >= -1.f && d.y <= 1.f) {
    long long c = ((long long)(ab * gw + (int)((d.x + 1.f) * sx))) * gh
                  + (int)((d.y + 1.f) * sy);
    if (c >= 0 && c < GRID_CAP) c1 = (int)c;
  }
  g_c0[id] = c0;
  g_c1[id] = c1;
  if (c0 >= 0) atomicMax(&g_grid0[c0], id + 1);
  if (c1 >= 0) atomicMax(&g_grid1[c1], id + 1);
}

// ---- k2: winners whose cell also holds a dst -> record; winner clears grid0 ----
// Safe: only the winner writes its cell, and it writes AFTER its own reads.
// Losers only read grid0[c0]; seeing either the winner's id or 0, both imply
// "not me". No thread writes grid1 here.
__global__ void k_collect() {
  int id = blockIdx.x * blockDim.x + threadIdx.x;
  int c0 = g_c0[id];
  if (c0 < 0) return;
  if (g_grid0[c0] != id + 1) return;   // not the max-id (last-write-wins) owner
  int v1 = g_grid1[c0];
  if (v1 != 0) {
    int slot = atomicAdd(&g_nm, 1);
    g_cell[slot] = c0;
    g_src[slot]  = id;
    g_dst[slot]  = v1 - 1;
  }
  g_grid0[c0] = 0;                     // restore invariant (winner-only write)
}

// ---- k3: clear grid1; emit record id at its row-major rank; pad the rest ----
// Perfect partition: matched ranks occupy rows [0,n), padding occupies [n,M).
__global__ void k_emit(const float* __restrict__ ps, const float* __restrict__ pd,
                       float* __restrict__ out,
                       const int* __restrict__ ph, const int* __restrict__ pw,
                       const int* __restrict__ pg) {
  int id = blockIdx.x * blockDim.x + threadIdx.x;
  int c1 = g_c1[id];
  if (c1 >= 0) g_grid1[c1] = 0;        // restore invariant (idempotent stores)

  int n = g_nm; if (n > MPTS) n = MPTS;

  float* out0 = out;               // src_coord_m [M,2]
  float* out1 = out + 2*MPTS;      // dst_coord_m [M,2]
  float* out2 = out + 4*MPTS;      // src_bn      [M,2]
  float* out3 = out + 6*MPTS;      // dst_an      [M,2]
  float* out4 = out + 8*MPTS;      // valid       [M]

  if (id < n) {
    int h = *ph, w = *pw, gs = *pg;
    int gh = h * gs, gw = w * gs;
    float sx = (float)((gw - 1) * 0.5);
    float sy = (float)((gh - 1) * 0.5);
    float fx = (float)((double)(h - 1) / (double)(gh - 1));  // pairs with x (faithful)
    float fy = (float)((double)(w - 1) / (double)(gw - 1));

    int ci = g_cell[id];
    int rank = 0;
    for (int j = 0; j < n; ++j) rank += (int)(g_cell[j] < ci);  // cells unique
    int s = g_src[id], d = g_dst[id];
    float2 a = ((const float2*)ps)[s];
    out0[2*rank]   = (a.x + 1.f) * sx * fx;
    out0[2*rank+1] = (a.y + 1.f) * sy * fy;
    float2 b = ((const float2*)pd)[d];
    out1[2*rank]   = (b.x + 1.f) * sx * fx;
    out1[2*rank+1] = (b.y + 1.f) * sy * fy;
    out2[2*rank]   = (float)((s / NP) % BD);
    out2[2*rank+1] = (float)(s % NP);
    out3[2*rank]   = (float)(d / (BD * NP));
    out3[2*rank+1] = (float)(d % NP);
    out4[rank]     = 1.f;
  } else {
    float2* o01 = (float2*)out;
    o01[id]          = make_float2(0.f, 0.f);    // src_coord_m
    o01[MPTS + id]   = make_float2(0.f, 0.f);    // dst_coord_m
    o01[2*MPTS + id] = make_float2(-1.f, -1.f);  // src_bn
    o01[3*MPTS + id] = make_float2(-1.f, -1.f);  // dst_an
    out4[id]         = 0.f;                      // valid
  }
}

extern "C" void kernel_launch(void* const* d_in, const int* in_sizes, int n_in,
                              void* d_out, int out_size, void* d_ws, size_t ws_size,
                              hipStream_t stream) {
  const float* ps = (const float*)d_in[0];
  const float* pd = (const float*)d_in[1];
  const int* ph = (const int*)d_in[2];
  const int* pw = (const int*)d_in[3];
  const int* pg = (const int*)d_in[4];
  float* out = (float*)d_out;

  k_scatter<<<MPTS/256, 256, 0, stream>>>(ps, pd, ph, pw, pg);
  k_collect<<<MPTS/256, 256, 0, stream>>>();
  k_emit   <<<MPTS/256, 256, 0, stream>>>(ps, pd, out, ph, pw, pg);
}

// Round 5
// 24.439 us; speedup vs baseline: 8.9115x; 1.0413x over previous
//
#include <hip/hip_runtime.h>

// GridMatch: A=8, B=8, N=2048, grid 640x480 per (a,b) image.
#define AD 8
#define BD 8
#define NP 2048
#define MPTS (AD*BD*NP)            // 131072 points
#define GRID_CAP 19660800LL        // 8*8*640*480 cells per grid

// Interleaved grids: g_grid[2c] = src (id+1), g_grid[2c+1] = dst (id+1); 0 = empty.
// Zero at module load; src halves cleared by winners in k_collect, dst halves by
// k_emit (idempotent overlap) -> both grids all-zero again after every call.
__device__ int g_grid[2*19660800];
__device__ int g_nm;               // match count (zeroed in k_scatter)
__device__ int2 g_cc[MPTS];        // saved cells per point: {c0, c1}, -1 = invisible
__device__ int g_cell[MPTS];       // unordered match records
__device__ int g_src[MPTS];
__device__ int g_dst[MPTS];

// ---- k1: compute cells (2 pts/thread), save them, atomicMax scatter ----
__global__ void k_scatter(const float* __restrict__ ps, const float* __restrict__ pd,
                          const int* __restrict__ ph, const int* __restrict__ pw,
                          const int* __restrict__ pg) {
  int t = blockIdx.x * blockDim.x + threadIdx.x;   // 0..MPTS/2-1
  if (t == 0) g_nm = 0;
  int h = *ph, w = *pw, gs = *pg;
  int gh = h * gs, gw = w * gs;
  float sx = (float)((gw - 1) * 0.5);
  float sy = (float)((gh - 1) * 0.5);

  float4 s2 = ((const float4*)ps)[t];   // points 2t, 2t+1 (x,y,x,y)
  float4 d2 = ((const float4*)pd)[t];

#pragma unroll
  for (int k = 0; k < 2; ++k) {
    int id = 2*t + k;
    int ab = id / NP;
    float px = k ? s2.z : s2.x, py = k ? s2.w : s2.y;
    int c0 = -1, c1 = -1;
    if (px >= -1.f && px <= 1.f && py >= -1.f && py <= 1.f) {
      long long c = ((long long)(ab * gw + (int)((px + 1.f) * sx))) * gh
                    + (int)((py + 1.f) * sy);
      if (c >= 0 && c < GRID_CAP) c0 = (int)c;
    }
    px = k ? d2.z : d2.x; py = k ? d2.w : d2.y;
    if (px >= -1.f && px <= 1.f && py >= -1.f && py <= 1.f) {
      long long c = ((long long)(ab * gw + (int)((px + 1.f) * sx))) * gh
                    + (int)((py + 1.f) * sy);
      if (c >= 0 && c < GRID_CAP) c1 = (int)c;
    }
    g_cc[id] = make_int2(c0, c1);
    if (c0 >= 0) atomicMax(&g_grid[2*c0],     id + 1);
    if (c1 >= 0) atomicMax(&g_grid[2*c1 + 1], id + 1);
  }
}

// ---- k2: src winners read {src,dst} in ONE 8B gather; record match; clear cell ----
// Safe: only the unique src winner of a cell writes it (after its own read).
// Losers read .x and see either winner-id or 0 -> both mean "not me".
__global__ void k_collect() {
  int t = blockIdx.x * blockDim.x + threadIdx.x;   // 0..MPTS/2-1
  int4 cc = ((const int4*)g_cc)[t];                // {c0,c1} of points 2t, 2t+1
#pragma unroll
  for (int k = 0; k < 2; ++k) {
    int id = 2*t + k;
    int c0 = k ? cc.z : cc.x;
    if (c0 < 0) continue;
    int2 v = *(const int2*)&g_grid[2*c0];          // one 8B gather: {src, dst}
    if (v.x != id + 1) continue;                   // not the last-write-wins owner
    if (v.y != 0) {
      int slot = atomicAdd(&g_nm, 1);
      g_cell[slot] = c0;
      g_src[slot]  = id;
      g_dst[slot]  = v.y - 1;
    }
    *(int2*)&g_grid[2*c0] = make_int2(0, 0);       // winner-only clear (both halves)
  }
}

// ---- k3: clear dst halves; emit record t at its row-major rank; pad rows >= n ----
// Perfect partition: matched ranks occupy rows [0,n), padding occupies [n,M).
__global__ void k_emit(const float* __restrict__ ps, const float* __restrict__ pd,
                       float* __restrict__ out,
                       const int* __restrict__ ph, const int* __restrict__ pw,
                       const int* __restrict__ pg) {
  int t = blockIdx.x * blockDim.x + threadIdx.x;   // 0..MPTS/2-1
  int4 cc = ((const int4*)g_cc)[t];
  if (cc.y >= 0) g_grid[2*cc.y + 1] = 0;           // idempotent dst-half clears
  if (cc.w >= 0) g_grid[2*cc.w + 1] = 0;

  int n = g_nm; if (n > MPTS) n = MPTS;

  float* out0 = out;               // src_coord_m [M,2]
  float* out1 = out + 2*MPTS;      // dst_coord_m [M,2]
  float* out2 = out + 4*MPTS;      // src_bn      [M,2]
  float* out3 = out + 6*MPTS;      // dst_an      [M,2]
  float* out4 = out + 8*MPTS;      // valid       [M]

  if (t < n) {                     // n <= 64*307200 occupied cells, << MPTS/2
    int h = *ph, w = *pw, gs = *pg;
    int gh = h * gs, gw = w * gs;
    float sx = (float)((gw - 1) * 0.5);
    float sy = (float)((gh - 1) * 0.5);
    float fx = (float)((double)(h - 1) / (double)(gh - 1));  // pairs with x (faithful)
    float fy = (float)((double)(w - 1) / (double)(gw - 1));

    int ci = g_cell[t];
    int rank = 0;
    for (int j = 0; j < n; ++j) rank += (int)(g_cell[j] < ci);  // cells unique
    int s = g_src[t], d = g_dst[t];
    float2 a = ((const float2*)ps)[s];
    out0[2*rank]   = (a.x + 1.f) * sx * fx;
    out0[2*rank+1] = (a.y + 1.f) * sy * fy;
    float2 b = ((const float2*)pd)[d];
    out1[2*rank]   = (b.x + 1.f) * sx * fx;
    out1[2*rank+1] = (b.y + 1.f) * sy * fy;
    out2[2*rank]   = (float)((s / NP) % BD);
    out2[2*rank+1] = (float)(s % NP);
    out3[2*rank]   = (float)(d / (BD * NP));
    out3[2*rank+1] = (float)(d % NP);
    out4[rank]     = 1.f;
  }

  // padding for rows r0=2t, r1=2t+1 (only rows >= n)
  int r0 = 2*t, r1 = 2*t + 1;
  if (r0 >= n) {                                   // both rows: float4 stores
    float4 z  = make_float4(0.f, 0.f, 0.f, 0.f);
    float4 m1 = make_float4(-1.f, -1.f, -1.f, -1.f);
    ((float4*)out0)[t] = z;
    ((float4*)out1)[t] = z;
    ((float4*)out2)[t] = m1;
    ((float4*)out3)[t] = m1;
    ((float2*)out4)[t] = make_float2(0.f, 0.f);
  } else if (r1 >= n) {                            // odd-n boundary: row r1 only
    float2 z2  = make_float2(0.f, 0.f);
    float2 m12 = make_float2(-1.f, -1.f);
    ((float2*)out0)[r1] = z2;
    ((float2*)out1)[r1] = z2;
    ((float2*)out2)[r1] = m12;
    ((float2*)out3)[r1] = m12;
    out4[r1] = 0.f;
  }
}

extern "C" void kernel_launch(void* const* d_in, const int* in_sizes, int n_in,
                              void* d_out, int out_size, void* d_ws, size_t ws_size,
                              hipStream_t stream) {
  const float* ps = (const float*)d_in[0];
  const float* pd = (const float*)d_in[1];
  const int* ph = (const int*)d_in[2];
  const int* pw = (const int*)d_in[3];
  const int* pg = (const int*)d_in[4];
  float* out = (float*)d_out;

  k_scatter<<<MPTS/512, 256, 0, stream>>>(ps, pd, ph, pw, pg);
  k_collect<<<MPTS/512, 256, 0, stream>>>();
  k_emit   <<<MPTS/512, 256, 0, stream>>>(ps, pd, out, ph, pw, pg);
}